// Round 12
// baseline (187.374 us; speedup 1.0000x reference)
//
#include <hip/hip_runtime.h>

#define NN 4096
#define IND 128
#define OUTD 64
#define WJ 128                 // j-window per wave per pipeline step
#define NWIN 8                 // windows per wave: 4 waves * 8 * 128 = 4096 j
#define LOG2E 1.44269504088896340736f

typedef __attribute__((ext_vector_type(4))) float  floatx4;
typedef __attribute__((ext_vector_type(8))) __bf16 bf16x8;
typedef __attribute__((ext_vector_type(4))) int    intx4;

#if __has_builtin(__builtin_amdgcn_exp2f)
#define EXP2(x) __builtin_amdgcn_exp2f(x)
#else
#define EXP2(x) exp2f(x)
#endif

__device__ __forceinline__ unsigned short f2bf(float f) {
  unsigned int u = __float_as_uint(f);
  u += 0x7fffu + ((u >> 16) & 1u);   // RNE; inputs are finite
  return (unsigned short)(u >> 16);
}

// ---------------- Kernel 1: Wh = H@W (fp32), s_a/s_b (log2e-scaled), whF bf16.
// whF is FRAGMENT-MAJOR: element (node j, channel c) at ((rel*512 + (j>>3))*64 + c)*8 + (j&7)
__global__ __launch_bounds__(256) void gat_prep(
    const float* __restrict__ H,
    const float* __restrict__ W0, const float* __restrict__ W1,
    const float* __restrict__ av0, const float* __restrict__ av1,
    unsigned short* __restrict__ whF,
    float* __restrict__ sA, float* __restrict__ sB)
{
  const int rel = blockIdx.y;
  const float* __restrict__ W  = rel ? W1 : W0;
  const float* __restrict__ av = rel ? av1 : av0;
  const int i0 = blockIdx.x * 16;
  const int t = threadIdx.x;
  const int c = t & 63;                                   // lane == output channel
  const int wv = __builtin_amdgcn_readfirstlane(t >> 6);  // wave -> 4 rows
  const float* __restrict__ hp = H + (size_t)(i0 + wv * 4) * IND;

  float acc0 = 0.f, acc1 = 0.f, acc2 = 0.f, acc3 = 0.f;
#pragma unroll 8
  for (int k = 0; k < IND; k += 4) {
    float4 h0 = *(const float4*)(hp + k);
    float4 h1 = *(const float4*)(hp + IND + k);
    float4 h2 = *(const float4*)(hp + 2 * IND + k);
    float4 h3 = *(const float4*)(hp + 3 * IND + k);
    float w0 = W[(k + 0) * OUTD + c];
    float w1 = W[(k + 1) * OUTD + c];
    float w2 = W[(k + 2) * OUTD + c];
    float w3 = W[(k + 3) * OUTD + c];
    acc0 += h0.x * w0 + h0.y * w1 + h0.z * w2 + h0.w * w3;
    acc1 += h1.x * w0 + h1.y * w1 + h1.z * w2 + h1.w * w3;
    acc2 += h2.x * w0 + h2.y * w1 + h2.z * w2 + h2.w * w3;
    acc3 += h3.x * w0 + h3.y * w1 + h3.z * w2 + h3.w * w3;
  }

  const float alo = av[c] * LOG2E, ahi = av[OUTD + c] * LOG2E;
  float pa0 = acc0 * alo, pa1 = acc1 * alo, pa2 = acc2 * alo, pa3 = acc3 * alo;
  float pb0 = acc0 * ahi, pb1 = acc1 * ahi, pb2 = acc2 * ahi, pb3 = acc3 * ahi;
#pragma unroll
  for (int off = 32; off >= 1; off >>= 1) {
    pa0 += __shfl_xor(pa0, off); pa1 += __shfl_xor(pa1, off);
    pa2 += __shfl_xor(pa2, off); pa3 += __shfl_xor(pa3, off);
    pb0 += __shfl_xor(pb0, off); pb1 += __shfl_xor(pb1, off);
    pb2 += __shfl_xor(pb2, off); pb3 += __shfl_xor(pb3, off);
  }
  const int ibase = i0 + wv * 4;
  if (c == 0) {
    float* sa = sA + rel * NN + ibase;
    float* sb = sB + rel * NN + ibase;
    sa[0] = pa0; sa[1] = pa1; sa[2] = pa2; sa[3] = pa3;
    sb[0] = pb0; sb[1] = pb1; sb[2] = pb2; sb[3] = pb3;
  }

  unsigned long long packed =
      (unsigned long long)f2bf(acc0)        | ((unsigned long long)f2bf(acc1) << 16) |
      ((unsigned long long)f2bf(acc2) << 32) | ((unsigned long long)f2bf(acc3) << 48);
  *(unsigned long long*)(whF + ((size_t)(rel * 512 + (ibase >> 3)) * 64 + c) * 8 + (ibase & 7)) = packed;
}

// ---------------- Kernel 2 (fused): R8 champion EXACTLY, except A loads are
// PLAIN (cached) instead of __builtin_nontemporal_load — single-variable A/B.
// A fits in L3 (134 MB < 256 MB) and is L3-warm from the harness restore.
__global__ __launch_bounds__(256, 2) void gat_fused(
    const int* __restrict__ A0, const int* __restrict__ A1,
    const unsigned short* __restrict__ whF,
    const float* __restrict__ sA, const float* __restrict__ sB,
    float* __restrict__ numer,          // [2][4096][64]
    float* __restrict__ denom)          // [2][4096]
{
  __shared__ char lds[4][2][4096];      // 4 waves x double-buffered 4 KB w-tile
  const int rel  = blockIdx.y;
  const int i0   = blockIdx.x * 16;
  const int t    = threadIdx.x;
  const int w    = t >> 6;
  const int lane = t & 63;
  const int quad = lane >> 4;
  const int m    = lane & 15;
  const int lj   = lane & 31;           // j-quad index (4 j per lane over 128-j window)
  const int half = lane >> 5;           // row-parity selector
  const int s_st = lj >> 1;             // staging 8-j slot
  const int wboff = s_st * 256 + (lj & 1) * 8;
  const int* __restrict__ A = rel ? A1 : A0;
  const unsigned short* __restrict__ wh = whF + (size_t)rel * 512 * 64 * 8;
  const float* __restrict__ sbp = sB + rel * NN;

  const float siv = sA[rel * NN + i0 + m];   // lane r (<16) holds s_i of row r
  const int jbase = w * (NWIN * WJ);         // wave's 1024-j span

  floatx4 acc0 = {0.f,0.f,0.f,0.f}, acc1 = acc0, acc2 = acc0, acc3 = acc0, acc4 = acc0;
  bf16x8 vone;
#pragma unroll
  for (int k = 0; k < 8; k++) vone[k] = (__bf16)1.0f;

  intx4  av2[2][8];                     // A double-buffer (one consumed, one in flight)
  float4 sjv2[2];
  bf16x8 b[4][4];                       // current window's B fragments

  auto issueA = [&](int win) {          // PLAIN cached loads (the R12 variable)
    const int jw = jbase + win * WJ;
    const int buf = win & 1;
    sjv2[buf] = *(const float4*)(sbp + jw + lj * 4);
    const int* pA = A + (size_t)(i0 + half) * NN + jw + lj * 4;
#pragma unroll
    for (int p = 0; p < 8; p++)
      av2[buf][p] = *(const intx4*)(pA + (size_t)(2 * p) * NN);
  };

  auto stage = [&](int win) {           // e(win) -> LDS buf[win&1]  (validated R5-R11)
    const int buf = win & 1;
    char* slice = lds[w][buf];
    const float4 sjv = sjv2[buf];
#pragma unroll
    for (int p = 0; p < 8; p++) {
      const int rp = 2 * p + half;
      const float si = __shfl(siv, rp);
      float t0 = si + sjv.x, t1 = si + sjv.y, t2 = si + sjv.z, t3 = si + sjv.w;
      float e0 = EXP2(fmaxf(t0, 0.2f * t0));
      float e1 = EXP2(fmaxf(t1, 0.2f * t1));
      float e2 = EXP2(fmaxf(t2, 0.2f * t2));
      float e3 = EXP2(fmaxf(t3, 0.2f * t3));
      const intx4 a4 = av2[buf][p];
      e0 = a4[0] ? e0 : 0.f;
      e1 = a4[1] ? e1 : 0.f;
      e2 = a4[2] ? e2 : 0.f;
      e3 = a4[3] ? e3 : 0.f;
      uint2 pk;
      pk.x = (unsigned)f2bf(e0) | ((unsigned)f2bf(e1) << 16);
      pk.y = (unsigned)f2bf(e2) | ((unsigned)f2bf(e3) << 16);
      *(uint2*)(slice + wboff + ((rp ^ s_st) & 15) * 16) = pk;
    }
  };

  auto issueB = [&](int win) {          // 16 lane-contiguous 16B loads from L2
    const int jw = jbase + win * WJ;
    const unsigned short* bb = wh + ((size_t)(jw >> 3) + quad) * 512 + (size_t)m * 8;
#pragma unroll
    for (int ks = 0; ks < 4; ks++)
#pragma unroll
      for (int nt = 0; nt < 4; nt++)
        b[ks][nt] = *(const bf16x8*)(bb + (size_t)ks * 2048 + nt * 128);
  };

  auto domfma = [&](int win) {          // prefetch all 4 LDS frags, then MFMA burst
    char* slice = lds[w][win & 1];
    bf16x8 afr[4];
#pragma unroll
    for (int ks = 0; ks < 4; ks++) {
      const int s = ks * 4 + quad;
      afr[ks] = *(const bf16x8*)(slice + s * 256 + ((m ^ s) & 15) * 16);
    }
#pragma unroll
    for (int ks = 0; ks < 4; ks++) {
      acc0 = __builtin_amdgcn_mfma_f32_16x16x32_bf16(afr[ks], b[ks][0], acc0, 0, 0, 0);
      acc1 = __builtin_amdgcn_mfma_f32_16x16x32_bf16(afr[ks], b[ks][1], acc1, 0, 0, 0);
      acc2 = __builtin_amdgcn_mfma_f32_16x16x32_bf16(afr[ks], b[ks][2], acc2, 0, 0, 0);
      acc3 = __builtin_amdgcn_mfma_f32_16x16x32_bf16(afr[ks], b[ks][3], acc3, 0, 0, 0);
      acc4 = __builtin_amdgcn_mfma_f32_16x16x32_bf16(afr[ks], vone,     acc4, 0, 0, 0);
    }
  };

  // ---- prime the pipeline
  issueA(0);
  stage(0);
  issueA(1);

#pragma unroll
  for (int win = 0; win < NWIN; win++) {
    issueB(win);                           // B(win) in flight
    if (win + 2 < NWIN) issueA(win + 2);   // A(win+2): covered by stage+mfma+issueB
    if (win + 1 < NWIN) stage(win + 1);    // consumes A(win+1); covers B(win) latency
    domfma(win);
  }

  // ---- epilogue: acc -> own slice0 (dead), dsum -> own slice1 (dead)
  float* redw  = (float*)lds[w][0];
  float* dredw = (float*)lds[w][1];
  // C/D layout: col = lane&15 (+16*nt), row = quad*4 + reg   [m89/m91]
#pragma unroll
  for (int r = 0; r < 4; r++) {
    const int row = quad * 4 + r;
    redw[row * 64 + 0 * 16 + m] = acc0[r];
    redw[row * 64 + 1 * 16 + m] = acc1[r];
    redw[row * 64 + 2 * 16 + m] = acc2[r];
    redw[row * 64 + 3 * 16 + m] = acc3[r];
  }
  if (m == 0) {
#pragma unroll
    for (int r = 0; r < 4; r++) dredw[quad * 4 + r] = acc4[r];
  }
  __syncthreads();

  const int c  = t & 63;
  const int r0 = t >> 6;
  const size_t base = (size_t)rel * NN;
#pragma unroll
  for (int rr = r0; rr < 16; rr += 4) {
    float nsum = 0.f, ds = 0.f;
#pragma unroll
    for (int ww = 0; ww < 4; ww++) {
      nsum += ((const float*)lds[ww][0])[rr * 64 + c];
      ds   += ((const float*)lds[ww][1])[rr];
    }
    numer[(base + i0 + rr) * OUTD + c] = nsum;
    if (c == 0) denom[base + i0 + rr] = ds;
  }
}

// ---------------- Kernel 3: out = n0/d0 + n1/d1 + bias
__global__ __launch_bounds__(256) void gat_combine(
    const float* __restrict__ numer, const float* __restrict__ denom,
    const float* __restrict__ bias, float* __restrict__ out)
{
  const int idx = blockIdx.x * 256 + threadIdx.x;  // float4 index, 65536 total
  const int i  = idx >> 4;
  const int c4 = idx & 15;
  const float4* nv = (const float4*)numer;

  float4 o = ((const float4*)bias)[c4];
#pragma unroll
  for (int rel = 0; rel < 2; rel++) {
    const size_t base = (size_t)rel * NN + i;
    float4 n = nv[base * 16 + c4];
    float  d = denom[base];
    float inv = d > 0.f ? 1.f / d : 0.f;   // isolated-row nan_to_num -> 0
    o.x += n.x * inv; o.y += n.y * inv; o.z += n.z * inv; o.w += n.w * inv;
  }
  ((float4*)out)[idx] = o;
}

extern "C" void kernel_launch(void* const* d_in, const int* in_sizes, int n_in,
                              void* d_out, int out_size, void* d_ws, size_t ws_size,
                              hipStream_t stream) {
  const float* H    = (const float*)d_in[0];
  const int*   A0   = (const int*)d_in[1];
  const int*   A1   = (const int*)d_in[2];
  const float* W0   = (const float*)d_in[3];
  const float* W1   = (const float*)d_in[4];
  const float* av0  = (const float*)d_in[5];
  const float* av1  = (const float*)d_in[6];
  const float* bias = (const float*)d_in[7];
  float* out = (float*)d_out;

  // ws layout: whF 1 MB | sA 32 KB | sB 32 KB | numer [2][4096][64] 2.1 MB | denom [2][4096]
  const size_t whF_b = (size_t)2 * 512 * 64 * 8 * 2;     // 1 MB
  const size_t s_b   = (size_t)2 * NN * 4;               // 32 KB each

  unsigned short* whF   = (unsigned short*)d_ws;
  float*          sA    = (float*)((char*)d_ws + whF_b);
  float*          sB    = (float*)((char*)d_ws + whF_b + s_b);
  float*          numer = (float*)((char*)d_ws + whF_b + 2 * s_b);
  float*          denom = numer + (size_t)2 * NN * OUTD;

  gat_prep<<<dim3(NN / 16, 2), 256, 0, stream>>>(H, W0, W1, av0, av1, whF, sA, sB);
  gat_fused<<<dim3(NN / 16, 2), 256, 0, stream>>>(A0, A1, whF, sA, sB, numer, denom);
  gat_combine<<<(NN * OUTD / 4) / 256, 256, 0, stream>>>(numer, denom, bias, out);
}

// Round 13
// 178.010 us; speedup vs baseline: 1.0526x; 1.0526x over previous
//
#include <hip/hip_runtime.h>

#define NN 4096
#define IND 128
#define OUTD 64
#define WJ 128                 // j-window per wave per pipeline step
#define NWIN 8                 // windows per wave: 4 waves * 8 * 128 = 4096 j
#define LOG2E 1.44269504088896340736f

typedef __attribute__((ext_vector_type(4))) float  floatx4;
typedef __attribute__((ext_vector_type(8))) __bf16 bf16x8;
typedef __attribute__((ext_vector_type(4))) int    intx4;

#if __has_builtin(__builtin_amdgcn_exp2f)
#define EXP2(x) __builtin_amdgcn_exp2f(x)
#else
#define EXP2(x) exp2f(x)
#endif

__device__ __forceinline__ unsigned short f2bf(float f) {
  unsigned int u = __float_as_uint(f);
  u += 0x7fffu + ((u >> 16) & 1u);   // RNE; inputs are finite
  return (unsigned short)(u >> 16);
}

// ---------------- Kernel 1: Wh = H@W (fp32), s_a/s_b (log2e-scaled), whF bf16.
// whF is FRAGMENT-MAJOR: element (node j, channel c) at ((rel*512 + (j>>3))*64 + c)*8 + (j&7)
__global__ __launch_bounds__(256) void gat_prep(
    const float* __restrict__ H,
    const float* __restrict__ W0, const float* __restrict__ W1,
    const float* __restrict__ av0, const float* __restrict__ av1,
    unsigned short* __restrict__ whF,
    float* __restrict__ sA, float* __restrict__ sB)
{
  const int rel = blockIdx.y;
  const float* __restrict__ W  = rel ? W1 : W0;
  const float* __restrict__ av = rel ? av1 : av0;
  const int i0 = blockIdx.x * 16;
  const int t = threadIdx.x;
  const int c = t & 63;                                   // lane == output channel
  const int wv = __builtin_amdgcn_readfirstlane(t >> 6);  // wave -> 4 rows
  const float* __restrict__ hp = H + (size_t)(i0 + wv * 4) * IND;

  float acc0 = 0.f, acc1 = 0.f, acc2 = 0.f, acc3 = 0.f;
#pragma unroll 8
  for (int k = 0; k < IND; k += 4) {
    float4 h0 = *(const float4*)(hp + k);
    float4 h1 = *(const float4*)(hp + IND + k);
    float4 h2 = *(const float4*)(hp + 2 * IND + k);
    float4 h3 = *(const float4*)(hp + 3 * IND + k);
    float w0 = W[(k + 0) * OUTD + c];
    float w1 = W[(k + 1) * OUTD + c];
    float w2 = W[(k + 2) * OUTD + c];
    float w3 = W[(k + 3) * OUTD + c];
    acc0 += h0.x * w0 + h0.y * w1 + h0.z * w2 + h0.w * w3;
    acc1 += h1.x * w0 + h1.y * w1 + h1.z * w2 + h1.w * w3;
    acc2 += h2.x * w0 + h2.y * w1 + h2.z * w2 + h2.w * w3;
    acc3 += h3.x * w0 + h3.y * w1 + h3.z * w2 + h3.w * w3;
  }

  const float alo = av[c] * LOG2E, ahi = av[OUTD + c] * LOG2E;
  float pa0 = acc0 * alo, pa1 = acc1 * alo, pa2 = acc2 * alo, pa3 = acc3 * alo;
  float pb0 = acc0 * ahi, pb1 = acc1 * ahi, pb2 = acc2 * ahi, pb3 = acc3 * ahi;
#pragma unroll
  for (int off = 32; off >= 1; off >>= 1) {
    pa0 += __shfl_xor(pa0, off); pa1 += __shfl_xor(pa1, off);
    pa2 += __shfl_xor(pa2, off); pa3 += __shfl_xor(pa3, off);
    pb0 += __shfl_xor(pb0, off); pb1 += __shfl_xor(pb1, off);
    pb2 += __shfl_xor(pb2, off); pb3 += __shfl_xor(pb3, off);
  }
  const int ibase = i0 + wv * 4;
  if (c == 0) {
    float* sa = sA + rel * NN + ibase;
    float* sb = sB + rel * NN + ibase;
    sa[0] = pa0; sa[1] = pa1; sa[2] = pa2; sa[3] = pa3;
    sb[0] = pb0; sb[1] = pb1; sb[2] = pb2; sb[3] = pb3;
  }

  unsigned long long packed =
      (unsigned long long)f2bf(acc0)        | ((unsigned long long)f2bf(acc1) << 16) |
      ((unsigned long long)f2bf(acc2) << 32) | ((unsigned long long)f2bf(acc3) << 48);
  *(unsigned long long*)(whF + ((size_t)(rel * 512 + (ibase >> 3)) * 64 + c) * 8 + (ibase & 7)) = packed;
}

// ---------------- Kernel 2 (fused): R8 champion (nt A loads, NWIN=8) with ONE
// change: per-lane si values preloaded into registers — NO ds_bpermute in the
// stage loop (removes 64 LDS-latency ops/wave coupled to staging ds_writes).
__global__ __launch_bounds__(256, 2) void gat_fused(
    const int* __restrict__ A0, const int* __restrict__ A1,
    const unsigned short* __restrict__ whF,
    const float* __restrict__ sA, const float* __restrict__ sB,
    float* __restrict__ numer,          // [2][4096][64]
    float* __restrict__ denom)          // [2][4096]
{
  __shared__ char lds[4][2][4096];      // 4 waves x double-buffered 4 KB w-tile
  const int rel  = blockIdx.y;
  const int i0   = blockIdx.x * 16;
  const int t    = threadIdx.x;
  const int w    = t >> 6;
  const int lane = t & 63;
  const int quad = lane >> 4;
  const int m    = lane & 15;
  const int lj   = lane & 31;           // j-quad index (4 j per lane over 128-j window)
  const int half = lane >> 5;           // row-parity selector
  const int s_st = lj >> 1;             // staging 8-j slot
  const int wboff = s_st * 256 + (lj & 1) * 8;
  const int* __restrict__ A = rel ? A1 : A0;
  const unsigned short* __restrict__ wh = whF + (size_t)rel * 512 * 64 * 8;
  const float* __restrict__ sbp = sB + rel * NN;

  // R13: per-lane si registers — lane's stage rows are rp = 2p + half
  float si_r[8];
#pragma unroll
  for (int p = 0; p < 8; p++) si_r[p] = sA[rel * NN + i0 + 2 * p + half];

  const int jbase = w * (NWIN * WJ);         // wave's 1024-j span

  floatx4 acc0 = {0.f,0.f,0.f,0.f}, acc1 = acc0, acc2 = acc0, acc3 = acc0, acc4 = acc0;
  bf16x8 vone;
#pragma unroll
  for (int k = 0; k < 8; k++) vone[k] = (__bf16)1.0f;

  intx4  av2[2][8];                     // A double-buffer (one consumed, one in flight)
  float4 sjv2[2];
  bf16x8 b[4][4];                       // current window's B fragments

  auto issueA = [&](int win) {          // nontemporal: R12 A/B proved nt is ~12us better
    const int jw = jbase + win * WJ;
    const int buf = win & 1;
    sjv2[buf] = *(const float4*)(sbp + jw + lj * 4);
    const int* pA = A + (size_t)(i0 + half) * NN + jw + lj * 4;
#pragma unroll
    for (int p = 0; p < 8; p++)
      av2[buf][p] = __builtin_nontemporal_load((const intx4*)(pA + (size_t)(2 * p) * NN));
  };

  auto stage = [&](int win) {           // e(win) -> LDS buf[win&1]; pure VALU now
    const int buf = win & 1;
    char* slice = lds[w][buf];
    const float4 sjv = sjv2[buf];
#pragma unroll
    for (int p = 0; p < 8; p++) {
      const int rp = 2 * p + half;
      const float si = si_r[p];
      float t0 = si + sjv.x, t1 = si + sjv.y, t2 = si + sjv.z, t3 = si + sjv.w;
      float e0 = EXP2(fmaxf(t0, 0.2f * t0));
      float e1 = EXP2(fmaxf(t1, 0.2f * t1));
      float e2 = EXP2(fmaxf(t2, 0.2f * t2));
      float e3 = EXP2(fmaxf(t3, 0.2f * t3));
      const intx4 a4 = av2[buf][p];
      e0 = a4[0] ? e0 : 0.f;
      e1 = a4[1] ? e1 : 0.f;
      e2 = a4[2] ? e2 : 0.f;
      e3 = a4[3] ? e3 : 0.f;
      uint2 pk;
      pk.x = (unsigned)f2bf(e0) | ((unsigned)f2bf(e1) << 16);
      pk.y = (unsigned)f2bf(e2) | ((unsigned)f2bf(e3) << 16);
      *(uint2*)(slice + wboff + ((rp ^ s_st) & 15) * 16) = pk;
    }
  };

  auto issueB = [&](int win) {          // 16 lane-contiguous 16B loads from L2
    const int jw = jbase + win * WJ;
    const unsigned short* bb = wh + ((size_t)(jw >> 3) + quad) * 512 + (size_t)m * 8;
#pragma unroll
    for (int ks = 0; ks < 4; ks++)
#pragma unroll
      for (int nt = 0; nt < 4; nt++)
        b[ks][nt] = *(const bf16x8*)(bb + (size_t)ks * 2048 + nt * 128);
  };

  auto domfma = [&](int win) {          // prefetch all 4 LDS frags, then MFMA burst
    char* slice = lds[w][win & 1];
    bf16x8 afr[4];
#pragma unroll
    for (int ks = 0; ks < 4; ks++) {
      const int s = ks * 4 + quad;
      afr[ks] = *(const bf16x8*)(slice + s * 256 + ((m ^ s) & 15) * 16);
    }
#pragma unroll
    for (int ks = 0; ks < 4; ks++) {
      acc0 = __builtin_amdgcn_mfma_f32_16x16x32_bf16(afr[ks], b[ks][0], acc0, 0, 0, 0);
      acc1 = __builtin_amdgcn_mfma_f32_16x16x32_bf16(afr[ks], b[ks][1], acc1, 0, 0, 0);
      acc2 = __builtin_amdgcn_mfma_f32_16x16x32_bf16(afr[ks], b[ks][2], acc2, 0, 0, 0);
      acc3 = __builtin_amdgcn_mfma_f32_16x16x32_bf16(afr[ks], b[ks][3], acc3, 0, 0, 0);
      acc4 = __builtin_amdgcn_mfma_f32_16x16x32_bf16(afr[ks], vone,     acc4, 0, 0, 0);
    }
  };

  // ---- prime the pipeline
  issueA(0);
  stage(0);
  issueA(1);

#pragma unroll
  for (int win = 0; win < NWIN; win++) {
    issueB(win);                           // B(win) in flight
    if (win + 2 < NWIN) issueA(win + 2);   // A(win+2): covered by stage+mfma+issueB
    if (win + 1 < NWIN) stage(win + 1);    // consumes A(win+1); covers B(win) latency
    domfma(win);
  }

  // ---- epilogue: acc -> own slice0 (dead), dsum -> own slice1 (dead)
  float* redw  = (float*)lds[w][0];
  float* dredw = (float*)lds[w][1];
  // C/D layout: col = lane&15 (+16*nt), row = quad*4 + reg   [m89/m91]
#pragma unroll
  for (int r = 0; r < 4; r++) {
    const int row = quad * 4 + r;
    redw[row * 64 + 0 * 16 + m] = acc0[r];
    redw[row * 64 + 1 * 16 + m] = acc1[r];
    redw[row * 64 + 2 * 16 + m] = acc2[r];
    redw[row * 64 + 3 * 16 + m] = acc3[r];
  }
  if (m == 0) {
#pragma unroll
    for (int r = 0; r < 4; r++) dredw[quad * 4 + r] = acc4[r];
  }
  __syncthreads();

  const int c  = t & 63;
  const int r0 = t >> 6;
  const size_t base = (size_t)rel * NN;
#pragma unroll
  for (int rr = r0; rr < 16; rr += 4) {
    float nsum = 0.f, ds = 0.f;
#pragma unroll
    for (int ww = 0; ww < 4; ww++) {
      nsum += ((const float*)lds[ww][0])[rr * 64 + c];
      ds   += ((const float*)lds[ww][1])[rr];
    }
    numer[(base + i0 + rr) * OUTD + c] = nsum;
    if (c == 0) denom[base + i0 + rr] = ds;
  }
}

// ---------------- Kernel 3: out = n0/d0 + n1/d1 + bias
__global__ __launch_bounds__(256) void gat_combine(
    const float* __restrict__ numer, const float* __restrict__ denom,
    const float* __restrict__ bias, float* __restrict__ out)
{
  const int idx = blockIdx.x * 256 + threadIdx.x;  // float4 index, 65536 total
  const int i  = idx >> 4;
  const int c4 = idx & 15;
  const float4* nv = (const float4*)numer;

  float4 o = ((const float4*)bias)[c4];
#pragma unroll
  for (int rel = 0; rel < 2; rel++) {
    const size_t base = (size_t)rel * NN + i;
    float4 n = nv[base * 16 + c4];
    float  d = denom[base];
    float inv = d > 0.f ? 1.f / d : 0.f;   // isolated-row nan_to_num -> 0
    o.x += n.x * inv; o.y += n.y * inv; o.z += n.z * inv; o.w += n.w * inv;
  }
  ((float4*)out)[idx] = o;
}

extern "C" void kernel_launch(void* const* d_in, const int* in_sizes, int n_in,
                              void* d_out, int out_size, void* d_ws, size_t ws_size,
                              hipStream_t stream) {
  const float* H    = (const float*)d_in[0];
  const int*   A0   = (const int*)d_in[1];
  const int*   A1   = (const int*)d_in[2];
  const float* W0   = (const float*)d_in[3];
  const float* W1   = (const float*)d_in[4];
  const float* av0  = (const float*)d_in[5];
  const float* av1  = (const float*)d_in[6];
  const float* bias = (const float*)d_in[7];
  float* out = (float*)d_out;

  // ws layout: whF 1 MB | sA 32 KB | sB 32 KB | numer [2][4096][64] 2.1 MB | denom [2][4096]
  const size_t whF_b = (size_t)2 * 512 * 64 * 8 * 2;     // 1 MB
  const size_t s_b   = (size_t)2 * NN * 4;               // 32 KB each

  unsigned short* whF   = (unsigned short*)d_ws;
  float*          sA    = (float*)((char*)d_ws + whF_b);
  float*          sB    = (float*)((char*)d_ws + whF_b + s_b);
  float*          numer = (float*)((char*)d_ws + whF_b + 2 * s_b);
  float*          denom = numer + (size_t)2 * NN * OUTD;

  gat_prep<<<dim3(NN / 16, 2), 256, 0, stream>>>(H, W0, W1, av0, av1, whF, sA, sB);
  gat_fused<<<dim3(NN / 16, 2), 256, 0, stream>>>(A0, A1, whF, sA, sB, numer, denom);
  gat_combine<<<(NN * OUTD / 4) / 256, 256, 0, stream>>>(numer, denom, bias, out);
}